// Round 16
// baseline (245.993 us; speedup 1.0000x reference)
//
#include <hip/hip_runtime.h>
#include <stdint.h>

#define NB 4096   // query rows
#define NM 8192   // memory rows
#define ND 1024   // feature dim

typedef __attribute__((ext_vector_type(8))) short bf16x8;
typedef __attribute__((ext_vector_type(4))) float f32x4;
typedef __attribute__((ext_vector_type(8))) unsigned short u16x8;
typedef __attribute__((ext_vector_type(4))) int i32x4;
typedef __attribute__((ext_vector_type(8))) int i32x8;

#define SCONE 0x7F7F7F7F   // e8m0 scales = 2^0  (uniform -> opsel-proof)
#define SCQ16 0x7B7B7B7B   // e8m0 scales = 2^-4 (uniform; undoes the x16 pre-scale)

static __device__ __forceinline__ unsigned short f2bf(float f) {
  union { float f; uint32_t u; } v; v.f = f;
  uint32_t u = v.u;
  u += 0x7fffu + ((u >> 16) & 1u);   // RNE
  return (unsigned short)(u >> 16);
}
static __device__ __forceinline__ float bf2f(unsigned short b) {
  union { uint32_t u; float f; } v; v.u = ((uint32_t)b) << 16; return v.f;
}
// fp32 -> OCP e4m3fn, RNE, saturating
static __device__ __forceinline__ uint8_t f2fp8(float f) {
  union { float f; uint32_t u; } v; v.f = f;
  const uint8_t s = (uint8_t)((v.u >> 31) << 7);
  const float a = fabsf(f);
  if (a >= 448.f) return s | 0x7E;
  if (a < 0.0009765625f) return s;            // < 2^-10 -> 0
  const uint32_t u = v.u & 0x7FFFFFFFu;
  const int e = (int)(u >> 23) - 127;
  if (e < -6) {                                // subnormal: m * 2^-9
    int m = (int)rintf(a * 512.f);
    if (m >= 8) return s | 0x08;
    return s | (uint8_t)m;
  }
  const uint32_t r = u + 0x7FFFFu + ((u >> 20) & 1u);  // RNE to 3-bit mant
  const int e2 = (int)(r >> 23) - 127;
  if (e2 > 8) return s | 0x7E;
  return s | (uint8_t)((e2 + 7) << 3) | (uint8_t)((r >> 20) & 7u);
}
// OCP e4m3fn -> fp32 (we never store NaN/0x7F)
static __device__ __forceinline__ float fp82f(uint8_t b) {
  const float sgn = (b & 0x80) ? -1.f : 1.f;
  const int e = (b >> 3) & 0xF, m = b & 7;
  if (e == 0) return sgn * (float)m * 0.001953125f;   // m * 2^-9
  union { uint32_t u; float f; } v;
  v.u = ((uint32_t)(e + 120) << 23) | ((uint32_t)m << 20);
  return sgn * v.f;
}

static __device__ __forceinline__ void gload_lds16(const void* g, void* l) {
  __builtin_amdgcn_global_load_lds(
      (__attribute__((address_space(1))) void*)g,
      (__attribute__((address_space(3))) void*)l, 16, 0, 0);
}

#define BAR()   __builtin_amdgcn_s_barrier()
#define LGKM0() asm volatile("s_waitcnt lgkmcnt(0)" ::: "memory")
#define VMC8()  asm volatile("s_waitcnt vmcnt(8)" ::: "memory")
#define VMC2()  asm volatile("s_waitcnt vmcnt(2)" ::: "memory")
#define VMC0()  asm volatile("s_waitcnt vmcnt(0)" ::: "memory")

// ---- normalize mem rows -> bf16 (memn) + fp8 (memn8) -----------------------
__global__ void nrm_m8(const float* __restrict__ x, unsigned short* __restrict__ ob,
                       uint8_t* __restrict__ o8) {
  const int row = blockIdx.x, t = threadIdx.x;
  const float4 v = ((const float4*)(x + (size_t)row * ND))[t];
  float ss = v.x * v.x + v.y * v.y + v.z * v.z + v.w * v.w;
  #pragma unroll
  for (int o = 32; o > 0; o >>= 1) ss += __shfl_xor(ss, o);
  __shared__ float red[4];
  if ((t & 63) == 0) red[t >> 6] = ss;
  __syncthreads();
  ss = (red[0] + red[1]) + (red[2] + red[3]);
  const float sc = 1.0f / fmaxf(sqrtf(ss), 1e-12f);
  ushort4 o4;
  o4.x = f2bf(v.x * sc); o4.y = f2bf(v.y * sc);
  o4.z = f2bf(v.z * sc); o4.w = f2bf(v.w * sc);
  ((ushort4*)(ob + (size_t)row * ND))[t] = o4;
  uchar4 c4;
  c4.x = f2fp8(v.x * sc); c4.y = f2fp8(v.y * sc);
  c4.z = f2fp8(v.z * sc); c4.w = f2fp8(v.w * sc);
  ((uchar4*)(o8 + (size_t)row * ND))[t] = c4;
}

// ---- normalize q rows -> fp8 only ------------------------------------------
__global__ void nrm_q8(const float* __restrict__ x, uint8_t* __restrict__ o8) {
  const int row = blockIdx.x, t = threadIdx.x;
  const float4 v = ((const float4*)(x + (size_t)row * ND))[t];
  float ss = v.x * v.x + v.y * v.y + v.z * v.z + v.w * v.w;
  #pragma unroll
  for (int o = 32; o > 0; o >>= 1) ss += __shfl_xor(ss, o);
  __shared__ float red[4];
  if ((t & 63) == 0) red[t >> 6] = ss;
  __syncthreads();
  ss = (red[0] + red[1]) + (red[2] + red[3]);
  const float sc = 1.0f / fmaxf(sqrtf(ss), 1e-12f);
  uchar4 c4;
  c4.x = f2fp8(v.x * sc); c4.y = f2fp8(v.y * sc);
  c4.z = f2fp8(v.z * sc); c4.w = f2fp8(v.w * sc);
  ((uchar4*)(o8 + (size_t)row * ND))[t] = c4;
}

// ---- transpose memn [8192x1024] bf16 -> memt8 [1024x8192] fp8 --------------
__global__ void tr8_kernel(const unsigned short* __restrict__ memn, uint8_t* __restrict__ memt8) {
  __shared__ unsigned short Ts[64][66];
  const int t = threadIdx.x;
  const int d0 = blockIdx.x * 64, m0 = blockIdx.y * 64;
  #pragma unroll
  for (int r = 0; r < 2; ++r) {
    const int lrow = r * 32 + (t >> 3);
    const int lcol = (t & 7) * 8;
    u16x8 v = *(const u16x8*)(memn + (size_t)(m0 + lrow) * ND + d0 + lcol);
    #pragma unroll
    for (int j = 0; j < 8; ++j) Ts[lcol + j][lrow] = v[j];
  }
  __syncthreads();
  #pragma unroll
  for (int r = 0; r < 2; ++r) {
    const int orow = r * 32 + (t >> 3);
    const int ocol = (t & 7) * 8;
    unsigned long long o = 0;
    #pragma unroll
    for (int j = 0; j < 8; ++j)
      o |= (unsigned long long)f2fp8(bf2f(Ts[orow][ocol + j])) << (8 * j);
    *(unsigned long long*)(memt8 + (size_t)(d0 + orow) * NM + m0 + ocol) = o;
  }
}

// ---- colsum partials: colpart[bm][d] = sum_{r in bm-slice} memn[r][d] ------
__global__ void colsum_part(const unsigned short* __restrict__ memn, float* __restrict__ colpart) {
  const int d = blockIdx.x * 256 + threadIdx.x;   // grid.x = 4
  const int bm = blockIdx.y;                       // grid.y = 32
  float s = 0.f;
  for (int r = 0; r < 256; ++r)
    s += bf2f(memn[(size_t)(bm * 256 + r) * ND + d]);
  colpart[bm * ND + d] = s;
}
__global__ void colred(const float* __restrict__ colpart, float* __restrict__ colsum) {
  const int d = blockIdx.x * 256 + threadIdx.x;    // grid 4
  float s = 0.f;
  #pragma unroll
  for (int k = 0; k < 32; ++k) s += colpart[k * ND + d];
  colsum[d] = s;
}

// ====== GEMM1: 256x256, MX-fp8 K=128, r10 ring. Out: X8 = fp8(16*(e-1)) =====
__global__ __launch_bounds__(512, 2) void gemm4x(
    const uint8_t* __restrict__ A, const uint8_t* __restrict__ B,
    uint8_t* __restrict__ X8, float* __restrict__ psum,
    int ld, int ldc, int mt, int kchunk)
{
  extern __shared__ char smem[];   // [buf][A 32K | B 32K] x2 = 128 KiB
  const int t = threadIdx.x;
  const int w = t >> 6, l = t & 63;
  const int wr = w >> 2, wc = w & 3;
  const int nwg = gridDim.x, cpx = nwg >> 3;
  const int id = (blockIdx.x & 7) * cpx + (blockIdx.x >> 3);  // XCD swizzle
  const int brow = id % mt, bcol = id / mt;
  const int nt = kchunk >> 7;          // 8 K-tiles of 128 (even)

  const int srow = l >> 3;
  const int scol = ((l & 7) ^ srow) << 4;
  const int lr = l & 15, lhi = l >> 4;
  const int swz = (l & 7) << 4;
  const int cb0 = (lhi * 32) ^ swz;
  const int cb1 = (lhi * 32 + 16) ^ swz;
  const int aoffr = (wr * 16 + lr) * 128;
  const int boffr = (wc * 16 + lr) * 128;

  const uint8_t* Ab = A + (size_t)(brow * 256 + w * 8 + srow) * ld + scol;
  const uint8_t* Bb = B + (size_t)(bcol * 256 + w * 8 + srow) * ld + scol;

  auto stageA = [&](int p, int h, int tau) {
    const int kt = (tau < nt ? tau : nt - 1) << 7;
    const uint8_t* g = Ab + (size_t)(h * 128) * ld + kt;
    char* d = smem + p * 65536 + h * 16384 + w * 1024;
    gload_lds16(g, d);
    gload_lds16(g + (size_t)64 * ld, d + 8192);
  };
  auto stageB = [&](int p, int h, int tau) {
    const int kt = (tau < nt ? tau : nt - 1) << 7;
    const uint8_t* g = Bb + (size_t)(h * 128) * ld + kt;
    char* d = smem + p * 65536 + 32768 + h * 16384 + w * 1024;
    gload_lds16(g, d);
    gload_lds16(g + (size_t)64 * ld, d + 8192);
  };
  auto ldA4 = [&](int p, int m, int c) -> i32x4 {
    return *(const i32x4*)(smem + p * 65536 + m * 4096 + aoffr + (c ? cb1 : cb0));
  };
  auto ldB4 = [&](int p, int nf, int c) -> i32x4 {
    return *(const i32x4*)(smem + p * 65536 + 32768 + nf * 8192 + boffr + (c ? cb1 : cb0));
  };

  f32x4 acc[8][4] = {};
  i32x8 alo[4], ahi[4], bloA[2], bloB[2], bhi[2];

  #define RDA4(DST, P, MB)                                                     \
    _Pragma("unroll")                                                          \
    for (int m_ = 0; m_ < 4; ++m_) {                                           \
      i32x4 lo_ = ldA4(P, (MB) + m_, 0), hi_ = ldA4(P, (MB) + m_, 1);          \
      i32x8 r_; r_[0]=lo_[0]; r_[1]=lo_[1]; r_[2]=lo_[2]; r_[3]=lo_[3];        \
      r_[4]=hi_[0]; r_[5]=hi_[1]; r_[6]=hi_[2]; r_[7]=hi_[3]; DST[m_] = r_; }
  #define RDB4(DST, P, NBASE)                                                  \
    _Pragma("unroll")                                                          \
    for (int n_ = 0; n_ < 2; ++n_) {                                           \
      i32x4 lo_ = ldB4(P, (NBASE) + n_, 0), hi_ = ldB4(P, (NBASE) + n_, 1);    \
      i32x8 r_; r_[0]=lo_[0]; r_[1]=lo_[1]; r_[2]=lo_[2]; r_[3]=lo_[3];        \
      r_[4]=hi_[0]; r_[5]=hi_[1]; r_[6]=hi_[2]; r_[7]=hi_[3]; DST[n_] = r_; }
  #define CL8(AF, BF, MO, NO)                                                  \
    __builtin_amdgcn_s_setprio(1);                                             \
    _Pragma("unroll")                                                          \
    for (int m_ = 0; m_ < 4; ++m_)                                             \
      _Pragma("unroll")                                                        \
      for (int n_ = 0; n_ < 2; ++n_)                                           \
        acc[(MO) + m_][(NO) + n_] =                                            \
            __builtin_amdgcn_mfma_scale_f32_16x16x128_f8f6f4(                  \
                AF[m_], BF[n_], acc[(MO) + m_][(NO) + n_],                     \
                0, 0, 0, SCONE, 0, SCONE);                                     \
    __builtin_amdgcn_s_setprio(0);

  stageA(0, 0, 0); stageA(0, 1, 0); stageB(0, 0, 0); stageB(0, 1, 0);
  stageA(1, 0, 1); stageA(1, 1, 1); stageB(1, 0, 1); stageB(1, 1, 1);
  VMC8();
  BAR();
  RDA4(alo, 0, 0);
  RDB4(bloA, 0, 0);

  const int niter = nt >> 1;
  for (int i = 0; i < niter; ++i) {
    const int t2 = 2 * i + 2, t3 = 2 * i + 3;
    LGKM0();
    CL8(alo, bloA, 0, 0);
    RDB4(bhi, 0, 2);
    BAR();
    LGKM0();
    CL8(alo, bhi, 0, 2);
    RDA4(ahi, 0, 4);
    stageB(0, 0, t2);
    VMC2();
    BAR();
    LGKM0();
    CL8(ahi, bhi, 4, 2);
    RDB4(bloB, 1, 0);
    stageB(0, 1, t2); stageA(0, 0, t2);
    BAR();
    LGKM0();
    CL8(ahi, bloA, 4, 0);
    RDA4(alo, 1, 0);
    stageA(0, 1, t2);
    BAR();
    LGKM0();
    CL8(alo, bloB, 0, 0);
    RDB4(bhi, 1, 2);
    BAR();
    LGKM0();
    CL8(alo, bhi, 0, 2);
    RDA4(ahi, 1, 4);
    stageB(1, 0, t3);
    VMC2();
    BAR();
    LGKM0();
    CL8(ahi, bhi, 4, 2);
    RDB4(bloA, 0, 0);
    stageB(1, 1, t3); stageA(1, 0, t3);
    BAR();
    LGKM0();
    CL8(ahi, bloB, 4, 0);
    RDA4(alo, 0, 0);
    stageA(1, 1, t3);
    BAR();
  }
  #undef RDA4
  #undef RDB4
  #undef CL8

  // epilogue: X8 = fp8(16*(exp(sim)-1)) + per-block row-sum partials of exp.
  const int crow0 = brow * 256 + wr * 16 + lhi * 4;
  const int ccol0 = bcol * 256 + wc * 16 + lr;
  float rs[8][4];
  #pragma unroll
  for (int m = 0; m < 8; ++m)
    #pragma unroll
    for (int j = 0; j < 4; ++j) rs[m][j] = 0.f;
  #pragma unroll
  for (int m = 0; m < 8; ++m)
    #pragma unroll
    for (int n = 0; n < 4; ++n)
      #pragma unroll
      for (int j = 0; j < 4; ++j) {
        const float e = __expf(acc[m][n][j]);
        rs[m][j] += e;
        X8[(size_t)(crow0 + m * 32 + j) * ldc + ccol0 + n * 64] = f2fp8(16.f * (e - 1.f));
      }
  #pragma unroll
  for (int m = 0; m < 8; ++m)
    #pragma unroll
    for (int j = 0; j < 4; ++j)
      #pragma unroll
      for (int o = 1; o < 16; o <<= 1) rs[m][j] += __shfl_xor(rs[m][j], o);
  VMC0();
  __syncthreads();
  float* ls = (float*)smem;
  if (lr == 0) {
    #pragma unroll
    for (int m = 0; m < 8; ++m)
      #pragma unroll
      for (int j = 0; j < 4; ++j)
        ls[wc * 256 + wr * 16 + m * 32 + lhi * 4 + j] = rs[m][j];
  }
  __syncthreads();
  if (t < 256) {
    const float s4 = ls[t] + ls[256 + t] + ls[512 + t] + ls[768 + t];
    psum[(size_t)bcol * NB + brow * 256 + t] = s4;
  }
}

// ---- sinv: 1/rowsum from psum[32][NB] --------------------------------------
__global__ void sinv_kernel(const float* __restrict__ psum, float* __restrict__ sinv) {
  const int row = blockIdx.x * 256 + threadIdx.x;
  float s = 0.f;
  #pragma unroll
  for (int k = 0; k < 32; ++k) s += psum[(size_t)k * NB + row];
  sinv[row] = 1.0f / s;
}

// ====== GEMM2: 256x256 MX-fp8 K=128, split-K partials + fused attn write ====
// part[ksp] = (X/16 via A-scale 2^-4) * memt8^T; attn = (1 + X/16)*sinv.
__global__ __launch_bounds__(512, 2) void gemm4y(
    const uint8_t* __restrict__ A, const uint8_t* __restrict__ B,
    float* __restrict__ C, const float* __restrict__ sinvp,
    float* __restrict__ attnp, int ld, int ldc, int mt, int tps, int kchunk,
    unsigned long long cstride)
{
  extern __shared__ char smem[];
  const int t = threadIdx.x;
  const int w = t >> 6, l = t & 63;
  const int wr = w >> 2, wc = w & 3;
  const int nwg = gridDim.x, cpx = nwg >> 3;
  const int id = (blockIdx.x & 7) * cpx + (blockIdx.x >> 3);
  const int ksp = id / tps, rem = id % tps;
  const int brow = rem % mt, bcol = rem / mt;
  const int k0 = ksp * kchunk;
  const int nt = kchunk >> 7;          // 16 K-tiles of 128 (even)

  const int srow = l >> 3;
  const int scol = ((l & 7) ^ srow) << 4;
  const int lr = l & 15, lhi = l >> 4;
  const int swz = (l & 7) << 4;
  const int cb0 = (lhi * 32) ^ swz;
  const int cb1 = (lhi * 32 + 16) ^ swz;
  const int aoffr = (wr * 16 + lr) * 128;
  const int boffr = (wc * 16 + lr) * 128;

  const uint8_t* Ab = A + (size_t)(brow * 256 + w * 8 + srow) * ld + k0 + scol;
  const uint8_t* Bb = B + (size_t)(bcol * 256 + w * 8 + srow) * ld + k0 + scol;

  auto stageA = [&](int p, int h, int tau) {
    const int kt = (tau < nt ? tau : nt - 1) << 7;
    const uint8_t* g = Ab + (size_t)(h * 128) * ld + kt;
    char* d = smem + p * 65536 + h * 16384 + w * 1024;
    gload_lds16(g, d);
    gload_lds16(g + (size_t)64 * ld, d + 8192);
  };
  auto stageB = [&](int p, int h, int tau) {
    const int kt = (tau < nt ? tau : nt - 1) << 7;
    const uint8_t* g = Bb + (size_t)(h * 128) * ld + kt;
    char* d = smem + p * 65536 + 32768 + h * 16384 + w * 1024;
    gload_lds16(g, d);
    gload_lds16(g + (size_t)64 * ld, d + 8192);
  };
  auto ldA4 = [&](int p, int m, int c) -> i32x4 {
    return *(const i32x4*)(smem + p * 65536 + m * 4096 + aoffr + (c ? cb1 : cb0));
  };
  auto ldB4 = [&](int p, int nf, int c) -> i32x4 {
    return *(const i32x4*)(smem + p * 65536 + 32768 + nf * 8192 + boffr + (c ? cb1 : cb0));
  };

  f32x4 acc[8][4] = {};
  i32x8 alo[4], ahi[4], bloA[2], bloB[2], bhi[2];

  #define RDA4(DST, P, MB)                                                     \
    _Pragma("unroll")                                                          \
    for (int m_ = 0; m_ < 4; ++m_) {                                           \
      i32x4 lo_ = ldA4(P, (MB) + m_, 0), hi_ = ldA4(P, (MB) + m_, 1);          \
      i32x8 r_; r_[0]=lo_[0]; r_[1]=lo_[1]; r_[2]=lo_[2]; r_[3]=lo_[3];        \
      r_[4]=hi_[0]; r_[5]=hi_[1]; r_[6]=hi_[2]; r_[7]=hi_[3]; DST[m_] = r_; }
  #define RDB4(DST, P, NBASE)                                                  \
    _Pragma("unroll")                                                          \
    for (int n_ = 0; n_ < 2; ++n_) {                                           \
      i32x4 lo_ = ldB4(P, (NBASE) + n_, 0), hi_ = ldB4(P, (NBASE) + n_, 1);    \
      i32x8 r_; r_[0]=lo_[0]; r_[1]=lo_[1]; r_[2]=lo_[2]; r_[3]=lo_[3];        \
      r_[4]=hi_[0]; r_[5]=hi_[1]; r_[6]=hi_[2]; r_[7]=hi_[3]; DST[n_] = r_; }
  #define CL8(AF, BF, MO, NO)                                                  \
    __builtin_amdgcn_s_setprio(1);                                             \
    _Pragma("unroll")                                                          \
    for (int m_ = 0; m_ < 4; ++m_)                                             \
      _Pragma("unroll")                                                        \
      for (int n_ = 0; n_ < 2; ++n_)                                           \
        acc[(MO) + m_][(NO) + n_] =                                            \
            __builtin_amdgcn_mfma_scale_f32_16x16x128_f8f6f4(                  \
                AF[m_], BF[n_], acc[(MO) + m_][(NO) + n_],                     \
                0, 0, 0, SCQ16, 0, SCONE);                                     \
    __builtin_amdgcn_s_setprio(0);

  stageA(0, 0, 0); stageA(0, 1, 0); stageB(0, 0, 0); stageB(0, 1, 0);
  stageA(1, 0, 1); stageA(1, 1, 1); stageB(1, 0, 1); stageB(1, 1, 1);
  VMC8();
  BAR();
  RDA4(alo, 0, 0);
  RDB4(bloA, 0, 0);

  const int niter = nt >> 1;
  for (int i = 0; i < niter; ++i) {
    const int t2 = 2 * i + 2, t3 = 2 * i + 3;
    LGKM0();
    CL8(alo, bloA, 0, 0);
    RDB4(bhi, 0, 2);
    BAR();
    LGKM0();
    CL8(alo, bhi, 0, 2);
    RDA4(ahi, 0, 4);
    stageB(0, 0, t2);
    VMC2();
    BAR();
    LGKM0();
    CL8(ahi, bhi, 4, 2);
    RDB4(bloB, 1, 0);
    stageB(0, 1, t2); stageA(0, 0, t2);
    BAR();
    LGKM0();
    CL8(ahi, bloA, 4, 0);
    RDA4(alo, 1, 0);
    stageA(0, 1, t2);
    BAR();
    LGKM0();
    CL8(alo, bloB, 0, 0);
    RDB4(bhi, 1, 2);
    BAR();
    LGKM0();
    CL8(alo, bhi, 0, 2);
    RDA4(ahi, 1, 4);
    stageB(1, 0, t3);
    VMC2();
    BAR();
    LGKM0();
    CL8(ahi, bhi, 4, 2);
    RDB4(bloA, 0, 0);
    stageB(1, 1, t3); stageA(1, 0, t3);
    BAR();
    LGKM0();
    CL8(ahi, bloB, 4, 0);
    RDA4(alo, 0, 0);
    stageA(1, 1, t3);
    BAR();
  }
  #undef RDA4
  #undef RDB4
  #undef CL8

  const int crow0 = brow * 256 + wr * 16 + lhi * 4;
  const int ccol0 = bcol * 256 + wc * 16 + lr;
  float* Cp = C + (unsigned long long)ksp * cstride;
  #pragma unroll
  for (int m = 0; m < 8; ++m)
    #pragma unroll
    for (int n = 0; n < 4; ++n)
      #pragma unroll
      for (int j = 0; j < 4; ++j)
        Cp[(size_t)(crow0 + m * 32 + j) * ldc + ccol0 + n * 64] = acc[m][n][j];

  // ---- fused attn write: rows r0..r0+63, cols k0..k0+kchunk ---------------
  {
    const int r0 = brow * 256 + bcol * 64;
    const int nch = kchunk >> 3;    // 8-byte chunks per row
    for (int idx = t; idx < 64 * nch; idx += 512) {
      const int row = idx / nch, ch = idx % nch;
      const float inv = sinvp[r0 + row];
      const unsigned long long bv =
          *(const unsigned long long*)(A + (size_t)(r0 + row) * ld + k0 + ch * 8);
      float4 f0, f1;
      #pragma unroll
      for (int j = 0; j < 8; ++j) {
        const float x = fp82f((uint8_t)(bv >> (8 * j)));
        const float a = (1.f + 0.0625f * x) * inv;
        if (j < 4) (&f0.x)[j] = a; else (&f1.x)[j - 4] = a;
      }
      float* arow = attnp + (size_t)(r0 + row) * NM + k0 + ch * 8;
      *(float4*)arow = f0;
      *(float4*)(arow + 4) = f1;
    }
  }
}

// ---- reduce: mf = (colsum[d] + sum_k part[k]) * sinv[row], S = 4 -----------
__global__ void reduce_kernel(const float4* __restrict__ part, float4* __restrict__ mf,
                              const float* __restrict__ sinv,
                              const float* __restrict__ colsum) {
  const size_t n4 = (size_t)NB * ND / 4;
  for (size_t i = (size_t)blockIdx.x * blockDim.x + threadIdx.x; i < n4;
       i += (size_t)gridDim.x * blockDim.x) {
    const float is = sinv[i >> 8];
    const float4 c4 = ((const float4*)colsum)[i & 255];
    float4 s = part[i];
    #pragma unroll
    for (int k = 1; k < 4; ++k) {
      float4 p = part[(size_t)k * n4 + i];
      s.x += p.x; s.y += p.y; s.z += p.z; s.w += p.w;
    }
    s.x = (s.x + c4.x) * is; s.y = (s.y + c4.y) * is;
    s.z = (s.z + c4.z) * is; s.w = (s.w + c4.w) * is;
    mf[i] = s;
  }
}

extern "C" void kernel_launch(void* const* d_in, const int* in_sizes, int n_in,
                              void* d_out, int out_size, void* d_ws, size_t ws_size,
                              hipStream_t stream) {
  const float* q   = (const float*)d_in[0];
  const float* mem = (const float*)d_in[1];
  float* mf   = (float*)d_out;                       // [4096 x 1024]
  float* attn = (float*)d_out + (size_t)NB * ND;     // [4096 x 8192]
  char* ws = (char*)d_ws;
  uint8_t* memn8       = (uint8_t*)(ws);                               // 8 MiB
  unsigned short* memn = (unsigned short*)(ws + ((size_t)8  << 20));   // 16 MiB
  uint8_t* memt8       = (uint8_t*)(ws + ((size_t)24 << 20));          // 8 MiB
  uint8_t* X8          = (uint8_t*)(ws + ((size_t)32 << 20));          // 32 MiB
  float* psum          = (float*)(ws + ((size_t)64 << 20));            // 512 KiB
  float* sinv          = (float*)(ws + ((size_t)64 << 20) + (512 << 10)); // 16 KiB
  float* colpart       = (float*)(ws + ((size_t)65 << 20));            // 128 KiB
  float* colsum        = (float*)(ws + ((size_t)65 << 20) + (512 << 10)); // 4 KiB
  float* part          = (float*)(ws + ((size_t)66 << 20));            // 64 MiB
  uint8_t* qn8         = (uint8_t*)(ws + ((size_t)130 << 20));         // 4 MiB

  hipFuncSetAttribute((const void*)gemm4x,
                      hipFuncAttributeMaxDynamicSharedMemorySize, 131072);
  hipFuncSetAttribute((const void*)gemm4y,
                      hipFuncAttributeMaxDynamicSharedMemorySize, 131072);

  hipLaunchKernelGGL(nrm_m8, dim3(NM), dim3(256), 0, stream, mem, memn, memn8);
  hipLaunchKernelGGL(nrm_q8, dim3(NB), dim3(256), 0, stream, q, qn8);
  hipLaunchKernelGGL(tr8_kernel, dim3(ND / 64, NM / 64), dim3(256), 0, stream, memn, memt8);
  hipLaunchKernelGGL(colsum_part, dim3(4, 32), dim3(256), 0, stream, memn, colpart);
  hipLaunchKernelGGL(colred, dim3(4), dim3(256), 0, stream, colpart, colsum);

  // X8 = fp8(16*(exp(qn8*memn8^T)-1)) + psum : MX-fp8, M=4096, N=8192, K=1024.
  hipLaunchKernelGGL(gemm4x, dim3((NB / 256) * (NM / 256)), dim3(512), 131072, stream,
                     qn8, memn8, X8, psum, ND, NM, NB / 256, ND);

  hipLaunchKernelGGL(sinv_kernel, dim3(NB / 256), dim3(256), 0, stream, psum, sinv);

  // part[k] = (X8*2^-4)*memt8^T (k-slice) + fused attn = (1+X/16)*sinv
  const int tps = (NB / 256) * (ND / 256);   // 64
  hipLaunchKernelGGL(gemm4y, dim3(tps * 4), dim3(512), 131072, stream,
                     X8, memt8, part, sinv, attn, NM, ND, NB / 256, tps, NM / 4,
                     (unsigned long long)NB * ND);
  hipLaunchKernelGGL(reduce_kernel, dim3(2048), dim3(256), 0, stream,
                     (const float4*)part, (float4*)mf, sinv, colsum);
}

// Round 17
// 187.716 us; speedup vs baseline: 1.3105x; 1.3105x over previous
//
#include <hip/hip_runtime.h>
#include <stdint.h>

#define NB 4096   // query rows
#define NM 8192   // memory rows
#define ND 1024   // feature dim

typedef __attribute__((ext_vector_type(8))) short bf16x8;
typedef __attribute__((ext_vector_type(4))) float f32x4;
typedef __attribute__((ext_vector_type(8))) unsigned short u16x8;
typedef __attribute__((ext_vector_type(4))) int i32x4;
typedef __attribute__((ext_vector_type(8))) int i32x8;

#define SCONE 0x7F7F7F7F   // e8m0 scales = 2^0  (uniform -> opsel-proof)
#define SCQ16 0x7B7B7B7B   // e8m0 scales = 2^-4 (uniform; undoes the x16 pre-scale)

static __device__ __forceinline__ unsigned short f2bf(float f) {
  union { float f; uint32_t u; } v; v.f = f;
  uint32_t u = v.u;
  u += 0x7fffu + ((u >> 16) & 1u);   // RNE
  return (unsigned short)(u >> 16);
}
static __device__ __forceinline__ float bf2f(unsigned short b) {
  union { uint32_t u; float f; } v; v.u = ((uint32_t)b) << 16; return v.f;
}
// fp32 -> OCP e4m3fn, RNE, saturating (software; used only in prep kernels)
static __device__ __forceinline__ uint8_t f2fp8(float f) {
  union { float f; uint32_t u; } v; v.f = f;
  const uint8_t s = (uint8_t)((v.u >> 31) << 7);
  const float a = fabsf(f);
  if (a >= 448.f) return s | 0x7E;
  if (a < 0.0009765625f) return s;            // < 2^-10 -> 0
  const uint32_t u = v.u & 0x7FFFFFFFu;
  const int e = (int)(u >> 23) - 127;
  if (e < -6) {                                // subnormal: m * 2^-9
    int m = (int)rintf(a * 512.f);
    if (m >= 8) return s | 0x08;
    return s | (uint8_t)m;
  }
  const uint32_t r = u + 0x7FFFFu + ((u >> 20) & 1u);  // RNE to 3-bit mant
  const int e2 = (int)(r >> 23) - 127;
  if (e2 > 8) return s | 0x7E;
  return s | (uint8_t)((e2 + 7) << 3) | (uint8_t)((r >> 20) & 7u);
}
// HW fp8 pack (gfx942+): branch-free, 1 VALU op — r17 fix for the gemm4x epilogue
static __device__ __forceinline__ uint8_t f2fp8_hw(float f) {
  return (uint8_t)(__builtin_amdgcn_cvt_pk_fp8_f32(f, f, 0, false) & 0xFF);
}
// OCP e4m3fn -> fp32 (we never store NaN/0x7F)
static __device__ __forceinline__ float fp82f(uint8_t b) {
  const float sgn = (b & 0x80) ? -1.f : 1.f;
  const int e = (b >> 3) & 0xF, m = b & 7;
  if (e == 0) return sgn * (float)m * 0.001953125f;   // m * 2^-9
  union { uint32_t u; float f; } v;
  v.u = ((uint32_t)(e + 120) << 23) | ((uint32_t)m << 20);
  return sgn * v.f;
}

static __device__ __forceinline__ void gload_lds16(const void* g, void* l) {
  __builtin_amdgcn_global_load_lds(
      (__attribute__((address_space(1))) void*)g,
      (__attribute__((address_space(3))) void*)l, 16, 0, 0);
}

#define BAR()   __builtin_amdgcn_s_barrier()
#define LGKM0() asm volatile("s_waitcnt lgkmcnt(0)" ::: "memory")
#define VMC8()  asm volatile("s_waitcnt vmcnt(8)" ::: "memory")
#define VMC2()  asm volatile("s_waitcnt vmcnt(2)" ::: "memory")
#define VMC0()  asm volatile("s_waitcnt vmcnt(0)" ::: "memory")

// ---- normalize mem rows -> bf16 (memn) + fp8 (memn8) -----------------------
__global__ void nrm_m8(const float* __restrict__ x, unsigned short* __restrict__ ob,
                       uint8_t* __restrict__ o8) {
  const int row = blockIdx.x, t = threadIdx.x;
  const float4 v = ((const float4*)(x + (size_t)row * ND))[t];
  float ss = v.x * v.x + v.y * v.y + v.z * v.z + v.w * v.w;
  #pragma unroll
  for (int o = 32; o > 0; o >>= 1) ss += __shfl_xor(ss, o);
  __shared__ float red[4];
  if ((t & 63) == 0) red[t >> 6] = ss;
  __syncthreads();
  ss = (red[0] + red[1]) + (red[2] + red[3]);
  const float sc = 1.0f / fmaxf(sqrtf(ss), 1e-12f);
  ushort4 o4;
  o4.x = f2bf(v.x * sc); o4.y = f2bf(v.y * sc);
  o4.z = f2bf(v.z * sc); o4.w = f2bf(v.w * sc);
  ((ushort4*)(ob + (size_t)row * ND))[t] = o4;
  uchar4 c4;
  c4.x = f2fp8(v.x * sc); c4.y = f2fp8(v.y * sc);
  c4.z = f2fp8(v.z * sc); c4.w = f2fp8(v.w * sc);
  ((uchar4*)(o8 + (size_t)row * ND))[t] = c4;
}

// ---- normalize q rows -> fp8 only ------------------------------------------
__global__ void nrm_q8(const float* __restrict__ x, uint8_t* __restrict__ o8) {
  const int row = blockIdx.x, t = threadIdx.x;
  const float4 v = ((const float4*)(x + (size_t)row * ND))[t];
  float ss = v.x * v.x + v.y * v.y + v.z * v.z + v.w * v.w;
  #pragma unroll
  for (int o = 32; o > 0; o >>= 1) ss += __shfl_xor(ss, o);
  __shared__ float red[4];
  if ((t & 63) == 0) red[t >> 6] = ss;
  __syncthreads();
  ss = (red[0] + red[1]) + (red[2] + red[3]);
  const float sc = 1.0f / fmaxf(sqrtf(ss), 1e-12f);
  uchar4 c4;
  c4.x = f2fp8(v.x * sc); c4.y = f2fp8(v.y * sc);
  c4.z = f2fp8(v.z * sc); c4.w = f2fp8(v.w * sc);
  ((uchar4*)(o8 + (size_t)row * ND))[t] = c4;
}

// ---- transpose memn [8192x1024] bf16 -> memt8 [1024x8192] fp8 --------------
__global__ void tr8_kernel(const unsigned short* __restrict__ memn, uint8_t* __restrict__ memt8) {
  __shared__ unsigned short Ts[64][66];
  const int t = threadIdx.x;
  const int d0 = blockIdx.x * 64, m0 = blockIdx.y * 64;
  #pragma unroll
  for (int r = 0; r < 2; ++r) {
    const int lrow = r * 32 + (t >> 3);
    const int lcol = (t & 7) * 8;
    u16x8 v = *(const u16x8*)(memn + (size_t)(m0 + lrow) * ND + d0 + lcol);
    #pragma unroll
    for (int j = 0; j < 8; ++j) Ts[lcol + j][lrow] = v[j];
  }
  __syncthreads();
  #pragma unroll
  for (int r = 0; r < 2; ++r) {
    const int orow = r * 32 + (t >> 3);
    const int ocol = (t & 7) * 8;
    unsigned long long o = 0;
    #pragma unroll
    for (int j = 0; j < 8; ++j)
      o |= (unsigned long long)f2fp8(bf2f(Ts[orow][ocol + j])) << (8 * j);
    *(unsigned long long*)(memt8 + (size_t)(d0 + orow) * NM + m0 + ocol) = o;
  }
}

// ---- colsum partials: colpart[bm][d] = sum_{r in bm-slice} memn[r][d] ------
__global__ void colsum_part(const unsigned short* __restrict__ memn, float* __restrict__ colpart) {
  const int d = blockIdx.x * 256 + threadIdx.x;   // grid.x = 4
  const int bm = blockIdx.y;                       // grid.y = 32
  float s = 0.f;
  for (int r = 0; r < 256; ++r)
    s += bf2f(memn[(size_t)(bm * 256 + r) * ND + d]);
  colpart[bm * ND + d] = s;
}
__global__ void colred(const float* __restrict__ colpart, float* __restrict__ colsum) {
  const int d = blockIdx.x * 256 + threadIdx.x;    // grid 4
  float s = 0.f;
  #pragma unroll
  for (int k = 0; k < 32; ++k) s += colpart[k * ND + d];
  colsum[d] = s;
}

// ====== GEMM1: 256x256, MX-fp8 K=128, r10 ring. Out: X8 = fp8(16*(e-1)) =====
// r17: epilogue fp8 pack via HW v_cvt_pk_fp8_f32 (branch-free) — r16's
// software f2fp8 (4 divergent paths x 128 unrolled) cost ~100us (spill/stall).
__global__ __launch_bounds__(512, 2) void gemm4x(
    const uint8_t* __restrict__ A, const uint8_t* __restrict__ B,
    uint8_t* __restrict__ X8, float* __restrict__ psum,
    int ld, int ldc, int mt, int kchunk)
{
  extern __shared__ char smem[];   // [buf][A 32K | B 32K] x2 = 128 KiB
  const int t = threadIdx.x;
  const int w = t >> 6, l = t & 63;
  const int wr = w >> 2, wc = w & 3;
  const int nwg = gridDim.x, cpx = nwg >> 3;
  const int id = (blockIdx.x & 7) * cpx + (blockIdx.x >> 3);  // XCD swizzle
  const int brow = id % mt, bcol = id / mt;
  const int nt = kchunk >> 7;          // 8 K-tiles of 128 (even)

  const int srow = l >> 3;
  const int scol = ((l & 7) ^ srow) << 4;
  const int lr = l & 15, lhi = l >> 4;
  const int swz = (l & 7) << 4;
  const int cb0 = (lhi * 32) ^ swz;
  const int cb1 = (lhi * 32 + 16) ^ swz;
  const int aoffr = (wr * 16 + lr) * 128;
  const int boffr = (wc * 16 + lr) * 128;

  const uint8_t* Ab = A + (size_t)(brow * 256 + w * 8 + srow) * ld + scol;
  const uint8_t* Bb = B + (size_t)(bcol * 256 + w * 8 + srow) * ld + scol;

  auto stageA = [&](int p, int h, int tau) {
    const int kt = (tau < nt ? tau : nt - 1) << 7;
    const uint8_t* g = Ab + (size_t)(h * 128) * ld + kt;
    char* d = smem + p * 65536 + h * 16384 + w * 1024;
    gload_lds16(g, d);
    gload_lds16(g + (size_t)64 * ld, d + 8192);
  };
  auto stageB = [&](int p, int h, int tau) {
    const int kt = (tau < nt ? tau : nt - 1) << 7;
    const uint8_t* g = Bb + (size_t)(h * 128) * ld + kt;
    char* d = smem + p * 65536 + 32768 + h * 16384 + w * 1024;
    gload_lds16(g, d);
    gload_lds16(g + (size_t)64 * ld, d + 8192);
  };
  auto ldA4 = [&](int p, int m, int c) -> i32x4 {
    return *(const i32x4*)(smem + p * 65536 + m * 4096 + aoffr + (c ? cb1 : cb0));
  };
  auto ldB4 = [&](int p, int nf, int c) -> i32x4 {
    return *(const i32x4*)(smem + p * 65536 + 32768 + nf * 8192 + boffr + (c ? cb1 : cb0));
  };

  f32x4 acc[8][4] = {};
  i32x8 alo[4], ahi[4], bloA[2], bloB[2], bhi[2];

  #define RDA4(DST, P, MB)                                                     \
    _Pragma("unroll")                                                          \
    for (int m_ = 0; m_ < 4; ++m_) {                                           \
      i32x4 lo_ = ldA4(P, (MB) + m_, 0), hi_ = ldA4(P, (MB) + m_, 1);          \
      i32x8 r_; r_[0]=lo_[0]; r_[1]=lo_[1]; r_[2]=lo_[2]; r_[3]=lo_[3];        \
      r_[4]=hi_[0]; r_[5]=hi_[1]; r_[6]=hi_[2]; r_[7]=hi_[3]; DST[m_] = r_; }
  #define RDB4(DST, P, NBASE)                                                  \
    _Pragma("unroll")                                                          \
    for (int n_ = 0; n_ < 2; ++n_) {                                           \
      i32x4 lo_ = ldB4(P, (NBASE) + n_, 0), hi_ = ldB4(P, (NBASE) + n_, 1);    \
      i32x8 r_; r_[0]=lo_[0]; r_[1]=lo_[1]; r_[2]=lo_[2]; r_[3]=lo_[3];        \
      r_[4]=hi_[0]; r_[5]=hi_[1]; r_[6]=hi_[2]; r_[7]=hi_[3]; DST[n_] = r_; }
  #define CL8(AF, BF, MO, NO)                                                  \
    __builtin_amdgcn_s_setprio(1);                                             \
    _Pragma("unroll")                                                          \
    for (int m_ = 0; m_ < 4; ++m_)                                             \
      _Pragma("unroll")                                                        \
      for (int n_ = 0; n_ < 2; ++n_)                                           \
        acc[(MO) + m_][(NO) + n_] =                                            \
            __builtin_amdgcn_mfma_scale_f32_16x16x128_f8f6f4(                  \
                AF[m_], BF[n_], acc[(MO) + m_][(NO) + n_],                     \
                0, 0, 0, SCONE, 0, SCONE);                                     \
    __builtin_amdgcn_s_setprio(0);

  stageA(0, 0, 0); stageA(0, 1, 0); stageB(0, 0, 0); stageB(0, 1, 0);
  stageA(1, 0, 1); stageA(1, 1, 1); stageB(1, 0, 1); stageB(1, 1, 1);
  VMC8();
  BAR();
  RDA4(alo, 0, 0);
  RDB4(bloA, 0, 0);

  const int niter = nt >> 1;
  for (int i = 0; i < niter; ++i) {
    const int t2 = 2 * i + 2, t3 = 2 * i + 3;
    LGKM0();
    CL8(alo, bloA, 0, 0);
    RDB4(bhi, 0, 2);
    BAR();
    LGKM0();
    CL8(alo, bhi, 0, 2);
    RDA4(ahi, 0, 4);
    stageB(0, 0, t2);
    VMC2();
    BAR();
    LGKM0();
    CL8(ahi, bhi, 4, 2);
    RDB4(bloB, 1, 0);
    stageB(0, 1, t2); stageA(0, 0, t2);
    BAR();
    LGKM0();
    CL8(ahi, bloA, 4, 0);
    RDA4(alo, 1, 0);
    stageA(0, 1, t2);
    BAR();
    LGKM0();
    CL8(alo, bloB, 0, 0);
    RDB4(bhi, 1, 2);
    BAR();
    LGKM0();
    CL8(alo, bhi, 0, 2);
    RDA4(ahi, 1, 4);
    stageB(1, 0, t3);
    VMC2();
    BAR();
    LGKM0();
    CL8(ahi, bhi, 4, 2);
    RDB4(bloA, 0, 0);
    stageB(1, 1, t3); stageA(1, 0, t3);
    BAR();
    LGKM0();
    CL8(ahi, bloB, 4, 0);
    RDA4(alo, 0, 0);
    stageA(1, 1, t3);
    BAR();
  }
  #undef RDA4
  #undef RDB4
  #undef CL8

  // epilogue: X8 = fp8_hw(16*(exp(sim)-1)) + per-block row-sum partials of exp.
  const int crow0 = brow * 256 + wr * 16 + lhi * 4;
  const int ccol0 = bcol * 256 + wc * 16 + lr;
  float rs[8][4];
  #pragma unroll
  for (int m = 0; m < 8; ++m)
    #pragma unroll
    for (int j = 0; j < 4; ++j) rs[m][j] = 0.f;
  #pragma unroll
  for (int m = 0; m < 8; ++m)
    #pragma unroll
    for (int n = 0; n < 4; ++n)
      #pragma unroll
      for (int j = 0; j < 4; ++j) {
        const float e = __expf(acc[m][n][j]);
        rs[m][j] += e;
        X8[(size_t)(crow0 + m * 32 + j) * ldc + ccol0 + n * 64] =
            f2fp8_hw(16.f * (e - 1.f));
      }
  #pragma unroll
  for (int m = 0; m < 8; ++m)
    #pragma unroll
    for (int j = 0; j < 4; ++j)
      #pragma unroll
      for (int o = 1; o < 16; o <<= 1) rs[m][j] += __shfl_xor(rs[m][j], o);
  VMC0();
  __syncthreads();
  float* ls = (float*)smem;
  if (lr == 0) {
    #pragma unroll
    for (int m = 0; m < 8; ++m)
      #pragma unroll
      for (int j = 0; j < 4; ++j)
        ls[wc * 256 + wr * 16 + m * 32 + lhi * 4 + j] = rs[m][j];
  }
  __syncthreads();
  if (t < 256) {
    const float s4 = ls[t] + ls[256 + t] + ls[512 + t] + ls[768 + t];
    psum[(size_t)bcol * NB + brow * 256 + t] = s4;
  }
}

// ---- sinv: 1/rowsum from psum[32][NB] --------------------------------------
__global__ void sinv_kernel(const float* __restrict__ psum, float* __restrict__ sinv) {
  const int row = blockIdx.x * 256 + threadIdx.x;
  float s = 0.f;
  #pragma unroll
  for (int k = 0; k < 32; ++k) s += psum[(size_t)k * NB + row];
  sinv[row] = 1.0f / s;
}

// ====== GEMM2: 256x256 MX-fp8 K=128, split-K partials + fused attn write ====
// part[ksp] = (X/16 via A-scale 2^-4) * memt8^T; attn = (1 + X/16)*sinv.
__global__ __launch_bounds__(512, 2) void gemm4y(
    const uint8_t* __restrict__ A, const uint8_t* __restrict__ B,
    float* __restrict__ C, const float* __restrict__ sinvp,
    float* __restrict__ attnp, int ld, int ldc, int mt, int tps, int kchunk,
    unsigned long long cstride)
{
  extern __shared__ char smem[];
  const int t = threadIdx.x;
  const int w = t >> 6, l = t & 63;
  const int wr = w >> 2, wc = w & 3;
  const int nwg = gridDim.x, cpx = nwg >> 3;
  const int id = (blockIdx.x & 7) * cpx + (blockIdx.x >> 3);
  const int ksp = id / tps, rem = id % tps;
  const int brow = rem % mt, bcol = rem / mt;
  const int k0 = ksp * kchunk;
  const int nt = kchunk >> 7;          // 16 K-tiles of 128 (even)

  const int srow = l >> 3;
  const int scol = ((l & 7) ^ srow) << 4;
  const int lr = l & 15, lhi = l >> 4;
  const int swz = (l & 7) << 4;
  const int cb0 = (lhi * 32) ^ swz;
  const int cb1 = (lhi * 32 + 16) ^ swz;
  const int aoffr = (wr * 16 + lr) * 128;
  const int boffr = (wc * 16 + lr) * 128;

  const uint8_t* Ab = A + (size_t)(brow * 256 + w * 8 + srow) * ld + k0 + scol;
  const uint8_t* Bb = B + (size_t)(bcol * 256 + w * 8 + srow) * ld + k0 + scol;

  auto stageA = [&](int p, int h, int tau) {
    const int kt = (tau < nt ? tau : nt - 1) << 7;
    const uint8_t* g = Ab + (size_t)(h * 128) * ld + kt;
    char* d = smem + p * 65536 + h * 16384 + w * 1024;
    gload_lds16(g, d);
    gload_lds16(g + (size_t)64 * ld, d + 8192);
  };
  auto stageB = [&](int p, int h, int tau) {
    const int kt = (tau < nt ? tau : nt - 1) << 7;
    const uint8_t* g = Bb + (size_t)(h * 128) * ld + kt;
    char* d = smem + p * 65536 + 32768 + h * 16384 + w * 1024;
    gload_lds16(g, d);
    gload_lds16(g + (size_t)64 * ld, d + 8192);
  };
  auto ldA4 = [&](int p, int m, int c) -> i32x4 {
    return *(const i32x4*)(smem + p * 65536 + m * 4096 + aoffr + (c ? cb1 : cb0));
  };
  auto ldB4 = [&](int p, int nf, int c) -> i32x4 {
    return *(const i32x4*)(smem + p * 65536 + 32768 + nf * 8192 + boffr + (c ? cb1 : cb0));
  };

  f32x4 acc[8][4] = {};
  i32x8 alo[4], ahi[4], bloA[2], bloB[2], bhi[2];

  #define RDA4(DST, P, MB)                                                     \
    _Pragma("unroll")                                                          \
    for (int m_ = 0; m_ < 4; ++m_) {                                           \
      i32x4 lo_ = ldA4(P, (MB) + m_, 0), hi_ = ldA4(P, (MB) + m_, 1);          \
      i32x8 r_; r_[0]=lo_[0]; r_[1]=lo_[1]; r_[2]=lo_[2]; r_[3]=lo_[3];        \
      r_[4]=hi_[0]; r_[5]=hi_[1]; r_[6]=hi_[2]; r_[7]=hi_[3]; DST[m_] = r_; }
  #define RDB4(DST, P, NBASE)                                                  \
    _Pragma("unroll")                                                          \
    for (int n_ = 0; n_ < 2; ++n_) {                                           \
      i32x4 lo_ = ldB4(P, (NBASE) + n_, 0), hi_ = ldB4(P, (NBASE) + n_, 1);    \
      i32x8 r_; r_[0]=lo_[0]; r_[1]=lo_[1]; r_[2]=lo_[2]; r_[3]=lo_[3];        \
      r_[4]=hi_[0]; r_[5]=hi_[1]; r_[6]=hi_[2]; r_[7]=hi_[3]; DST[n_] = r_; }
  #define CL8(AF, BF, MO, NO)                                                  \
    __builtin_amdgcn_s_setprio(1);                                             \
    _Pragma("unroll")                                                          \
    for (int m_ = 0; m_ < 4; ++m_)                                             \
      _Pragma("unroll")                                                        \
      for (int n_ = 0; n_ < 2; ++n_)                                           \
        acc[(MO) + m_][(NO) + n_] =                                            \
            __builtin_amdgcn_mfma_scale_f32_16x16x128_f8f6f4(                  \
                AF[m_], BF[n_], acc[(MO) + m_][(NO) + n_],                     \
                0, 0, 0, SCQ16, 0, SCONE);                                     \
    __builtin_amdgcn_s_setprio(0);

  stageA(0, 0, 0); stageA(0, 1, 0); stageB(0, 0, 0); stageB(0, 1, 0);
  stageA(1, 0, 1); stageA(1, 1, 1); stageB(1, 0, 1); stageB(1, 1, 1);
  VMC8();
  BAR();
  RDA4(alo, 0, 0);
  RDB4(bloA, 0, 0);

  const int niter = nt >> 1;
  for (int i = 0; i < niter; ++i) {
    const int t2 = 2 * i + 2, t3 = 2 * i + 3;
    LGKM0();
    CL8(alo, bloA, 0, 0);
    RDB4(bhi, 0, 2);
    BAR();
    LGKM0();
    CL8(alo, bhi, 0, 2);
    RDA4(ahi, 0, 4);
    stageB(0, 0, t2);
    VMC2();
    BAR();
    LGKM0();
    CL8(ahi, bhi, 4, 2);
    RDB4(bloB, 1, 0);
    stageB(0, 1, t2); stageA(0, 0, t2);
    BAR();
    LGKM0();
    CL8(ahi, bloA, 4, 0);
    RDA4(alo, 1, 0);
    stageA(0, 1, t2);
    BAR();
    LGKM0();
    CL8(alo, bloB, 0, 0);
    RDB4(bhi, 1, 2);
    BAR();
    LGKM0();
    CL8(alo, bhi, 0, 2);
    RDA4(ahi, 1, 4);
    stageB(1, 0, t3);
    VMC2();
    BAR();
    LGKM0();
    CL8(ahi, bhi, 4, 2);
    RDB4(bloA, 0, 0);
    stageB(1, 1, t3); stageA(1, 0, t3);
    BAR();
    LGKM0();
    CL8(ahi, bloB, 4, 0);
    RDA4(alo, 0, 0);
    stageA(1, 1, t3);
    BAR();
  }
  #undef RDA4
  #undef RDB4
  #undef CL8

  const int crow0 = brow * 256 + wr * 16 + lhi * 4;
  const int ccol0 = bcol * 256 + wc * 16 + lr;
  float* Cp = C + (unsigned long long)ksp * cstride;
  #pragma unroll
  for (int m = 0; m < 8; ++m)
    #pragma unroll
    for (int n = 0; n < 4; ++n)
      #pragma unroll
      for (int j = 0; j < 4; ++j)
        Cp[(size_t)(crow0 + m * 32 + j) * ldc + ccol0 + n * 64] = acc[m][n][j];

  // ---- fused attn write: rows r0..r0+63, cols k0..k0+kchunk ---------------
  {
    const int r0 = brow * 256 + bcol * 64;
    const int nch = kchunk >> 3;    // 8-byte chunks per row
    for (int idx = t; idx < 64 * nch; idx += 512) {
      const int row = idx / nch, ch = idx % nch;
      const float inv = sinvp[r0 + row];
      const unsigned long long bv =
          *(const unsigned long long*)(A + (size_t)(r0 + row) * ld + k0 + ch * 8);
      float4 f0, f1;
      #pragma unroll
      for (int j = 0; j < 8; ++j) {
        const float x = fp82f((uint8_t)(bv >> (8 * j)));
        const float a = (1.f + 0.0625f * x) * inv;
        if (j < 4) (&f0.x)[j] = a; else (&f1.x)[j - 4] = a;
      }
      float* arow = attnp + (size_t)(r0 + row) * NM + k0 + ch * 8;
      *(float4*)arow = f0;
      *(float4*)(arow + 4) = f1;
    }
  }
}

// ---- reduce: mf = (colsum[d] + sum_k part[k]) * sinv[row], S = 4 -----------
__global__ void reduce_kernel(const float4* __restrict__ part, float4* __restrict__ mf,
                              const float* __restrict__ sinv,
                              const float* __restrict__ colsum) {
  const size_t n4 = (size_t)NB * ND / 4;
  for (size_t i = (size_t)blockIdx.x * blockDim.x + threadIdx.x; i < n4;
       i += (size_t)gridDim.x * blockDim.x) {
    const float is = sinv[i >> 8];
    const float4 c4 = ((const float4*)colsum)[i & 255];
    float4 s = part[i];
    #pragma unroll
    for (int k = 1; k < 4; ++k) {
      float4 p = part[(size_t)k * n4 + i];
      s.x += p.x; s.y += p.y; s.z += p.z; s.w += p.w;
    }
    s.x = (s.x + c4.x) * is; s.y = (s.y + c4.y) * is;
    s.z = (s.z + c4.z) * is; s.w = (s.w + c4.w) * is;
    mf[i] = s;
  }
}

extern "C" void kernel_launch(void* const* d_in, const int* in_sizes, int n_in,
                              void* d_out, int out_size, void* d_ws, size_t ws_size,
                              hipStream_t stream) {
  const float* q   = (const float*)d_in[0];
  const float* mem = (const float*)d_in[1];
  float* mf   = (float*)d_out;                       // [4096 x 1024]
  float* attn = (float*)d_out + (size_t)NB * ND;     // [4096 x 8192]
  char* ws = (char*)d_ws;
  uint8_t* memn8       = (uint8_t*)(ws);                               // 8 MiB
  unsigned short* memn = (unsigned short*)(ws + ((size_t)8  << 20));   // 16 MiB
  uint8_t* memt8       = (uint8_t*)(ws + ((size_t)24 << 20));          // 8 MiB
  uint8_t* X8          = (uint8_t*)(ws + ((size_t)32 << 20));          // 32 MiB
  float* psum          = (float*)(ws + ((size_t)64 << 20));            // 512 KiB
  float* sinv          = (float*)(ws + ((size_t)64 << 20) + (512 << 10)); // 16 KiB
  float* colpart       = (float*)(ws + ((size_t)65 << 20));            // 128 KiB
  float* colsum        = (float*)(ws + ((size_t)65 << 20) + (512 << 10)); // 4 KiB
  float* part          = (float*)(ws + ((size_t)66 << 20));            // 64 MiB
  uint8_t* qn8         = (uint8_t*)(ws + ((size_t)130 << 20));         // 4 MiB

  hipFuncSetAttribute((const void*)gemm4x,
                      hipFuncAttributeMaxDynamicSharedMemorySize, 131072);
  hipFuncSetAttribute((const void*)gemm4y,
                      hipFuncAttributeMaxDynamicSharedMemorySize, 131072);

  hipLaunchKernelGGL(nrm_m8, dim3(NM), dim3(256), 0, stream, mem, memn, memn8);
  hipLaunchKernelGGL(nrm_q8, dim3(NB), dim3(256), 0, stream, q, qn8);
  hipLaunchKernelGGL(tr8_kernel, dim3(ND / 64, NM / 64), dim3(256), 0, stream, memn, memt8);
  hipLaunchKernelGGL(colsum_part, dim3(4, 32), dim3(256), 0, stream, memn, colpart);
  hipLaunchKernelGGL(colred, dim3(4), dim3(256), 0, stream, colpart, colsum);

  // X8 = fp8(16*(exp(qn8*memn8^T)-1)) + psum : MX-fp8, M=4096, N=8192, K=1024.
  hipLaunchKernelGGL(gemm4x, dim3((NB / 256) * (NM / 256)), dim3(512), 131072, stream,
                     qn8, memn8, X8, psum, ND, NM, NB / 256, ND);

  hipLaunchKernelGGL(sinv_kernel, dim3(NB / 256), dim3(256), 0, stream, psum, sinv);

  // part[k] = (X8*2^-4)*memt8^T (k-slice) + fused attn = (1+X/16)*sinv
  const int tps = (NB / 256) * (ND / 256);   // 64
  hipLaunchKernelGGL(gemm4y, dim3(tps * 4), dim3(512), 131072, stream,
                     X8, memt8, part, sinv, attn, NM, ND, NB / 256, tps, NM / 4,
                     (unsigned long long)NB * ND);
  hipLaunchKernelGGL(reduce_kernel, dim3(2048), dim3(256), 0, stream,
                     (const float4*)part, (float4*)mf, sinv, colsum);
}

// Round 18
// 169.127 us; speedup vs baseline: 1.4545x; 1.1099x over previous
//
#include <hip/hip_runtime.h>
#include <stdint.h>

#define NB 4096   // query rows
#define NM 8192   // memory rows
#define ND 1024   // feature dim

typedef __attribute__((ext_vector_type(8))) short bf16x8;
typedef __attribute__((ext_vector_type(4))) float f32x4;
typedef __attribute__((ext_vector_type(8))) unsigned short u16x8;
typedef __attribute__((ext_vector_type(4))) int i32x4;
typedef __attribute__((ext_vector_type(8))) int i32x8;

#define SCONE 0x7F7F7F7F   // e8m0 scales = 2^0  (uniform -> opsel-proof)
#define SCQ16 0x7B7B7B7B   // e8m0 scales = 2^-4 (undoes the x16 pre-scale)

static __device__ __forceinline__ unsigned short f2bf(float f) {
  union { float f; uint32_t u; } v; v.f = f;
  uint32_t u = v.u;
  u += 0x7fffu + ((u >> 16) & 1u);   // RNE
  return (unsigned short)(u >> 16);
}
static __device__ __forceinline__ float bf2f(unsigned short b) {
  union { uint32_t u; float f; } v; v.u = ((uint32_t)b) << 16; return v.f;
}
// HW fp8 pack (gfx942+): branch-free, 1 VALU op. OCP e4m3 on gfx950.
static __device__ __forceinline__ uint8_t f2fp8_hw(float f) {
  return (uint8_t)(__builtin_amdgcn_cvt_pk_fp8_f32(f, f, 0, false) & 0xFF);
}
// pack 4 floats -> 4 fp8 bytes via 2 HW pk-converts
static __device__ __forceinline__ uint32_t pk4_fp8(float a, float b, float c, float d) {
  uint32_t lo = __builtin_amdgcn_cvt_pk_fp8_f32(a, b, 0, false) & 0xFFFFu;
  uint32_t hi = __builtin_amdgcn_cvt_pk_fp8_f32(c, d, 0, false) & 0xFFFFu;
  return lo | (hi << 16);
}
// OCP e4m3fn -> fp32 (we never store NaN/0x7F)
static __device__ __forceinline__ float fp82f(uint8_t b) {
  const float sgn = (b & 0x80) ? -1.f : 1.f;
  const int e = (b >> 3) & 0xF, m = b & 7;
  if (e == 0) return sgn * (float)m * 0.001953125f;   // m * 2^-9
  union { uint32_t u; float f; } v;
  v.u = ((uint32_t)(e + 120) << 23) | ((uint32_t)m << 20);
  return sgn * v.f;
}

static __device__ __forceinline__ void gload_lds16(const void* g, void* l) {
  __builtin_amdgcn_global_load_lds(
      (__attribute__((address_space(1))) void*)g,
      (__attribute__((address_space(3))) void*)l, 16, 0, 0);
}

#define BAR()   __builtin_amdgcn_s_barrier()
#define LGKM0() asm volatile("s_waitcnt lgkmcnt(0)" ::: "memory")
#define VMC8()  asm volatile("s_waitcnt vmcnt(8)" ::: "memory")
#define VMC2()  asm volatile("s_waitcnt vmcnt(2)" ::: "memory")
#define VMC0()  asm volatile("s_waitcnt vmcnt(0)" ::: "memory")

// ---- normalize mem rows -> bf16 (memn) + fp8 (memn8); HW cvt ---------------
__global__ void nrm_m8(const float* __restrict__ x, unsigned short* __restrict__ ob,
                       uint8_t* __restrict__ o8) {
  const int row = blockIdx.x, t = threadIdx.x;
  const float4 v = ((const float4*)(x + (size_t)row * ND))[t];
  float ss = v.x * v.x + v.y * v.y + v.z * v.z + v.w * v.w;
  #pragma unroll
  for (int o = 32; o > 0; o >>= 1) ss += __shfl_xor(ss, o);
  __shared__ float red[4];
  if ((t & 63) == 0) red[t >> 6] = ss;
  __syncthreads();
  ss = (red[0] + red[1]) + (red[2] + red[3]);
  const float sc = 1.0f / fmaxf(sqrtf(ss), 1e-12f);
  ushort4 o4;
  o4.x = f2bf(v.x * sc); o4.y = f2bf(v.y * sc);
  o4.z = f2bf(v.z * sc); o4.w = f2bf(v.w * sc);
  ((ushort4*)(ob + (size_t)row * ND))[t] = o4;
  ((uint32_t*)(o8 + (size_t)row * ND))[t] =
      pk4_fp8(v.x * sc, v.y * sc, v.z * sc, v.w * sc);
}

// ---- normalize q rows -> fp8 only; HW cvt ----------------------------------
__global__ void nrm_q8(const float* __restrict__ x, uint8_t* __restrict__ o8) {
  const int row = blockIdx.x, t = threadIdx.x;
  const float4 v = ((const float4*)(x + (size_t)row * ND))[t];
  float ss = v.x * v.x + v.y * v.y + v.z * v.z + v.w * v.w;
  #pragma unroll
  for (int o = 32; o > 0; o >>= 1) ss += __shfl_xor(ss, o);
  __shared__ float red[4];
  if ((t & 63) == 0) red[t >> 6] = ss;
  __syncthreads();
  ss = (red[0] + red[1]) + (red[2] + red[3]);
  const float sc = 1.0f / fmaxf(sqrtf(ss), 1e-12f);
  ((uint32_t*)(o8 + (size_t)row * ND))[t] =
      pk4_fp8(v.x * sc, v.y * sc, v.z * sc, v.w * sc);
}

// ---- transpose memn [8192x1024] bf16 -> memt8 [1024x8192] fp8; HW cvt ------
__global__ void tr8_kernel(const unsigned short* __restrict__ memn, uint8_t* __restrict__ memt8) {
  __shared__ unsigned short Ts[64][66];
  const int t = threadIdx.x;
  const int d0 = blockIdx.x * 64, m0 = blockIdx.y * 64;
  #pragma unroll
  for (int r = 0; r < 2; ++r) {
    const int lrow = r * 32 + (t >> 3);
    const int lcol = (t & 7) * 8;
    u16x8 v = *(const u16x8*)(memn + (size_t)(m0 + lrow) * ND + d0 + lcol);
    #pragma unroll
    for (int j = 0; j < 8; ++j) Ts[lcol + j][lrow] = v[j];
  }
  __syncthreads();
  #pragma unroll
  for (int r = 0; r < 2; ++r) {
    const int orow = r * 32 + (t >> 3);
    const int ocol = (t & 7) * 8;
    uint32_t lo = pk4_fp8(bf2f(Ts[orow][ocol + 0]), bf2f(Ts[orow][ocol + 1]),
                          bf2f(Ts[orow][ocol + 2]), bf2f(Ts[orow][ocol + 3]));
    uint32_t hi = pk4_fp8(bf2f(Ts[orow][ocol + 4]), bf2f(Ts[orow][ocol + 5]),
                          bf2f(Ts[orow][ocol + 6]), bf2f(Ts[orow][ocol + 7]));
    *(unsigned long long*)(memt8 + (size_t)(d0 + orow) * NM + m0 + ocol) =
        ((unsigned long long)hi << 32) | lo;
  }
}

// ---- colsum partials: colpart[bm][d] = sum_{r in bm-slice} memn[r][d] ------
__global__ void colsum_part(const unsigned short* __restrict__ memn, float* __restrict__ colpart) {
  const int d = blockIdx.x * 256 + threadIdx.x;   // grid.x = 4
  const int bm = blockIdx.y;                       // grid.y = 32
  float s = 0.f;
  for (int r = 0; r < 256; ++r)
    s += bf2f(memn[(size_t)(bm * 256 + r) * ND + d]);
  colpart[bm * ND + d] = s;
}
__global__ void colred(const float* __restrict__ colpart, float* __restrict__ colsum) {
  const int d = blockIdx.x * 256 + threadIdx.x;    // grid 4
  float s = 0.f;
  #pragma unroll
  for (int k = 0; k < 32; ++k) s += colpart[k * ND + d];
  colsum[d] = s;
}

// ====== GEMM1: 256x256, MX-fp8 K=128, r10 ring. Out: X8 = fp8(16*(e-1)) =====
__global__ __launch_bounds__(512, 2) void gemm4x(
    const uint8_t* __restrict__ A, const uint8_t* __restrict__ B,
    uint8_t* __restrict__ X8, float* __restrict__ psum,
    int ld, int ldc, int mt, int kchunk)
{
  extern __shared__ char smem[];   // [buf][A 32K | B 32K] x2 = 128 KiB
  const int t = threadIdx.x;
  const int w = t >> 6, l = t & 63;
  const int wr = w >> 2, wc = w & 3;
  const int nwg = gridDim.x, cpx = nwg >> 3;
  const int id = (blockIdx.x & 7) * cpx + (blockIdx.x >> 3);  // XCD swizzle
  const int brow = id % mt, bcol = id / mt;
  const int nt = kchunk >> 7;          // 8 K-tiles of 128 (even)

  const int srow = l >> 3;
  const int scol = ((l & 7) ^ srow) << 4;
  const int lr = l & 15, lhi = l >> 4;
  const int swz = (l & 7) << 4;
  const int cb0 = (lhi * 32) ^ swz;
  const int cb1 = (lhi * 32 + 16) ^ swz;
  const int aoffr = (wr * 16 + lr) * 128;
  const int boffr = (wc * 16 + lr) * 128;

  const uint8_t* Ab = A + (size_t)(brow * 256 + w * 8 + srow) * ld + scol;
  const uint8_t* Bb = B + (size_t)(bcol * 256 + w * 8 + srow) * ld + scol;

  auto stageA = [&](int p, int h, int tau) {
    const int kt = (tau < nt ? tau : nt - 1) << 7;
    const uint8_t* g = Ab + (size_t)(h * 128) * ld + kt;
    char* d = smem + p * 65536 + h * 16384 + w * 1024;
    gload_lds16(g, d);
    gload_lds16(g + (size_t)64 * ld, d + 8192);
  };
  auto stageB = [&](int p, int h, int tau) {
    const int kt = (tau < nt ? tau : nt - 1) << 7;
    const uint8_t* g = Bb + (size_t)(h * 128) * ld + kt;
    char* d = smem + p * 65536 + 32768 + h * 16384 + w * 1024;
    gload_lds16(g, d);
    gload_lds16(g + (size_t)64 * ld, d + 8192);
  };
  auto ldA4 = [&](int p, int m, int c) -> i32x4 {
    return *(const i32x4*)(smem + p * 65536 + m * 4096 + aoffr + (c ? cb1 : cb0));
  };
  auto ldB4 = [&](int p, int nf, int c) -> i32x4 {
    return *(const i32x4*)(smem + p * 65536 + 32768 + nf * 8192 + boffr + (c ? cb1 : cb0));
  };

  f32x4 acc[8][4] = {};
  i32x8 alo[4], ahi[4], bloA[2], bloB[2], bhi[2];

  #define RDA4(DST, P, MB)                                                     \
    _Pragma("unroll")                                                          \
    for (int m_ = 0; m_ < 4; ++m_) {                                           \
      i32x4 lo_ = ldA4(P, (MB) + m_, 0), hi_ = ldA4(P, (MB) + m_, 1);          \
      i32x8 r_; r_[0]=lo_[0]; r_[1]=lo_[1]; r_[2]=lo_[2]; r_[3]=lo_[3];        \
      r_[4]=hi_[0]; r_[5]=hi_[1]; r_[6]=hi_[2]; r_[7]=hi_[3]; DST[m_] = r_; }
  #define RDB4(DST, P, NBASE)                                                  \
    _Pragma("unroll")                                                          \
    for (int n_ = 0; n_ < 2; ++n_) {                                           \
      i32x4 lo_ = ldB4(P, (NBASE) + n_, 0), hi_ = ldB4(P, (NBASE) + n_, 1);    \
      i32x8 r_; r_[0]=lo_[0]; r_[1]=lo_[1]; r_[2]=lo_[2]; r_[3]=lo_[3];        \
      r_[4]=hi_[0]; r_[5]=hi_[1]; r_[6]=hi_[2]; r_[7]=hi_[3]; DST[n_] = r_; }
  #define CL8(AF, BF, MO, NO)                                                  \
    __builtin_amdgcn_s_setprio(1);                                             \
    _Pragma("unroll")                                                          \
    for (int m_ = 0; m_ < 4; ++m_)                                             \
      _Pragma("unroll")                                                        \
      for (int n_ = 0; n_ < 2; ++n_)                                           \
        acc[(MO) + m_][(NO) + n_] =                                            \
            __builtin_amdgcn_mfma_scale_f32_16x16x128_f8f6f4(                  \
                AF[m_], BF[n_], acc[(MO) + m_][(NO) + n_],                     \
                0, 0, 0, SCONE, 0, SCONE);                                     \
    __builtin_amdgcn_s_setprio(0);

  stageA(0, 0, 0); stageA(0, 1, 0); stageB(0, 0, 0); stageB(0, 1, 0);
  stageA(1, 0, 1); stageA(1, 1, 1); stageB(1, 0, 1); stageB(1, 1, 1);
  VMC8();
  BAR();
  RDA4(alo, 0, 0);
  RDB4(bloA, 0, 0);

  const int niter = nt >> 1;
  for (int i = 0; i < niter; ++i) {
    const int t2 = 2 * i + 2, t3 = 2 * i + 3;
    LGKM0();
    CL8(alo, bloA, 0, 0);
    RDB4(bhi, 0, 2);
    BAR();
    LGKM0();
    CL8(alo, bhi, 0, 2);
    RDA4(ahi, 0, 4);
    stageB(0, 0, t2);
    VMC2();
    BAR();
    LGKM0();
    CL8(ahi, bhi, 4, 2);
    RDB4(bloB, 1, 0);
    stageB(0, 1, t2); stageA(0, 0, t2);
    BAR();
    LGKM0();
    CL8(ahi, bloA, 4, 0);
    RDA4(alo, 1, 0);
    stageA(0, 1, t2);
    BAR();
    LGKM0();
    CL8(alo, bloB, 0, 0);
    RDB4(bhi, 1, 2);
    BAR();
    LGKM0();
    CL8(alo, bhi, 0, 2);
    RDA4(ahi, 1, 4);
    stageB(1, 0, t3);
    VMC2();
    BAR();
    LGKM0();
    CL8(ahi, bhi, 4, 2);
    RDB4(bloA, 0, 0);
    stageB(1, 1, t3); stageA(1, 0, t3);
    BAR();
    LGKM0();
    CL8(ahi, bloB, 4, 0);
    RDA4(alo, 0, 0);
    stageA(1, 1, t3);
    BAR();
  }
  #undef RDA4
  #undef RDB4
  #undef CL8

  // epilogue: X8 = fp8_hw(16*(exp(sim)-1)) + per-block row-sum partials.
  const int crow0 = brow * 256 + wr * 16 + lhi * 4;
  const int ccol0 = bcol * 256 + wc * 16 + lr;
  float rs[8][4];
  #pragma unroll
  for (int m = 0; m < 8; ++m)
    #pragma unroll
    for (int j = 0; j < 4; ++j) rs[m][j] = 0.f;
  #pragma unroll
  for (int m = 0; m < 8; ++m)
    #pragma unroll
    for (int n = 0; n < 4; ++n)
      #pragma unroll
      for (int j = 0; j < 4; ++j) {
        const float e = __expf(acc[m][n][j]);
        rs[m][j] += e;
        X8[(size_t)(crow0 + m * 32 + j) * ldc + ccol0 + n * 64] =
            f2fp8_hw(16.f * (e - 1.f));
      }
  #pragma unroll
  for (int m = 0; m < 8; ++m)
    #pragma unroll
    for (int j = 0; j < 4; ++j)
      #pragma unroll
      for (int o = 1; o < 16; o <<= 1) rs[m][j] += __shfl_xor(rs[m][j], o);
  VMC0();
  __syncthreads();
  float* ls = (float*)smem;
  if (lr == 0) {
    #pragma unroll
    for (int m = 0; m < 8; ++m)
      #pragma unroll
      for (int j = 0; j < 4; ++j)
        ls[wc * 256 + wr * 16 + m * 32 + lhi * 4 + j] = rs[m][j];
  }
  __syncthreads();
  if (t < 256) {
    const float s4 = ls[t] + ls[256 + t] + ls[512 + t] + ls[768 + t];
    psum[(size_t)bcol * NB + brow * 256 + t] = s4;
  }
}

// ---- sinv: 1/rowsum from psum[32][NB] --------------------------------------
__global__ void sinv_kernel(const float* __restrict__ psum, float* __restrict__ sinv) {
  const int row = blockIdx.x * 256 + threadIdx.x;
  float s = 0.f;
  #pragma unroll
  for (int k = 0; k < 32; ++k) s += psum[(size_t)k * NB + row];
  sinv[row] = 1.0f / s;
}

// ====== GEMM2: 256x256 MX-fp8 K=128, split-K bf16 partials + fused attn =====
// part[ksp] (bf16) = (X/16 via A-scale 2^-4) * memt8^T; attn = (1+X/16)*sinv.
__global__ __launch_bounds__(512, 2) void gemm4y(
    const uint8_t* __restrict__ A, const uint8_t* __restrict__ B,
    unsigned short* __restrict__ C, const float* __restrict__ sinvp,
    float* __restrict__ attnp, int ld, int ldc, int mt, int tps, int kchunk,
    unsigned long long cstride)
{
  extern __shared__ char smem[];
  const int t = threadIdx.x;
  const int w = t >> 6, l = t & 63;
  const int wr = w >> 2, wc = w & 3;
  const int nwg = gridDim.x, cpx = nwg >> 3;
  const int id = (blockIdx.x & 7) * cpx + (blockIdx.x >> 3);
  const int ksp = id / tps, rem = id % tps;
  const int brow = rem % mt, bcol = rem / mt;
  const int k0 = ksp * kchunk;
  const int nt = kchunk >> 7;          // 16 K-tiles of 128 (even)

  const int srow = l >> 3;
  const int scol = ((l & 7) ^ srow) << 4;
  const int lr = l & 15, lhi = l >> 4;
  const int swz = (l & 7) << 4;
  const int cb0 = (lhi * 32) ^ swz;
  const int cb1 = (lhi * 32 + 16) ^ swz;
  const int aoffr = (wr * 16 + lr) * 128;
  const int boffr = (wc * 16 + lr) * 128;

  const uint8_t* Ab = A + (size_t)(brow * 256 + w * 8 + srow) * ld + k0 + scol;
  const uint8_t* Bb = B + (size_t)(bcol * 256 + w * 8 + srow) * ld + k0 + scol;

  auto stageA = [&](int p, int h, int tau) {
    const int kt = (tau < nt ? tau : nt - 1) << 7;
    const uint8_t* g = Ab + (size_t)(h * 128) * ld + kt;
    char* d = smem + p * 65536 + h * 16384 + w * 1024;
    gload_lds16(g, d);
    gload_lds16(g + (size_t)64 * ld, d + 8192);
  };
  auto stageB = [&](int p, int h, int tau) {
    const int kt = (tau < nt ? tau : nt - 1) << 7;
    const uint8_t* g = Bb + (size_t)(h * 128) * ld + kt;
    char* d = smem + p * 65536 + 32768 + h * 16384 + w * 1024;
    gload_lds16(g, d);
    gload_lds16(g + (size_t)64 * ld, d + 8192);
  };
  auto ldA4 = [&](int p, int m, int c) -> i32x4 {
    return *(const i32x4*)(smem + p * 65536 + m * 4096 + aoffr + (c ? cb1 : cb0));
  };
  auto ldB4 = [&](int p, int nf, int c) -> i32x4 {
    return *(const i32x4*)(smem + p * 65536 + 32768 + nf * 8192 + boffr + (c ? cb1 : cb0));
  };

  f32x4 acc[8][4] = {};
  i32x8 alo[4], ahi[4], bloA[2], bloB[2], bhi[2];

  #define RDA4(DST, P, MB)                                                     \
    _Pragma("unroll")                                                          \
    for (int m_ = 0; m_ < 4; ++m_) {                                           \
      i32x4 lo_ = ldA4(P, (MB) + m_, 0), hi_ = ldA4(P, (MB) + m_, 1);          \
      i32x8 r_; r_[0]=lo_[0]; r_[1]=lo_[1]; r_[2]=lo_[2]; r_[3]=lo_[3];        \
      r_[4]=hi_[0]; r_[5]=hi_[1]; r_[6]=hi_[2]; r_[7]=hi_[3]; DST[m_] = r_; }
  #define RDB4(DST, P, NBASE)                                                  \
    _Pragma("unroll")                                                          \
    for (int n_ = 0; n_ < 2; ++n_) {                                           \
      i32x4 lo_ = ldB4(P, (NBASE) + n_, 0), hi_ = ldB4(P, (NBASE) + n_, 1);    \
      i32x8 r_; r_[0]=lo_[0]; r_[1]=lo_[1]; r_[2]=lo_[2]; r_[3]=lo_[3];        \
      r_[4]=hi_[0]; r_[5]=hi_[1]; r_[6]=hi_[2]; r_[7]=hi_[3]; DST[n_] = r_; }
  #define CL8(AF, BF, MO, NO)                                                  \
    __builtin_amdgcn_s_setprio(1);                                             \
    _Pragma("unroll")                                                          \
    for (int m_ = 0; m_ < 4; ++m_)                                             \
      _Pragma("unroll")                                                        \
      for (int n_ = 0; n_ < 2; ++n_)                                           \
        acc[(MO) + m_][(NO) + n_] =                                            \
            __builtin_amdgcn_mfma_scale_f32_16x16x128_f8f6f4(                  \
                AF[m_], BF[n_], acc[(MO) + m_][(NO) + n_],                     \
                0, 0, 0, SCQ16, 0, SCONE);                                     \
    __builtin_amdgcn_s_setprio(0);

  stageA(0, 0, 0); stageA(0, 1, 0); stageB(0, 0, 0); stageB(0, 1, 0);
  stageA(1, 0, 1); stageA(1, 1, 1); stageB(1, 0, 1); stageB(1, 1, 1);
  VMC8();
  BAR();
  RDA4(alo, 0, 0);
  RDB4(bloA, 0, 0);

  const int niter = nt >> 1;
  for (int i = 0; i < niter; ++i) {
    const int t2 = 2 * i + 2, t3 = 2 * i + 3;
    LGKM0();
    CL8(alo, bloA, 0, 0);
    RDB4(bhi, 0, 2);
    BAR();
    LGKM0();
    CL8(alo, bhi, 0, 2);
    RDA4(ahi, 0, 4);
    stageB(0, 0, t2);
    VMC2();
    BAR();
    LGKM0();
    CL8(ahi, bhi, 4, 2);
    RDB4(bloB, 1, 0);
    stageB(0, 1, t2); stageA(0, 0, t2);
    BAR();
    LGKM0();
    CL8(ahi, bloA, 4, 0);
    RDA4(alo, 1, 0);
    stageA(0, 1, t2);
    BAR();
    LGKM0();
    CL8(alo, bloB, 0, 0);
    RDB4(bhi, 1, 2);
    BAR();
    LGKM0();
    CL8(alo, bhi, 0, 2);
    RDA4(ahi, 1, 4);
    stageB(1, 0, t3);
    VMC2();
    BAR();
    LGKM0();
    CL8(ahi, bhi, 4, 2);
    RDB4(bloA, 0, 0);
    stageB(1, 1, t3); stageA(1, 0, t3);
    BAR();
    LGKM0();
    CL8(ahi, bloB, 4, 0);
    RDA4(alo, 0, 0);
    stageA(1, 1, t3);
    BAR();
  }
  #undef RDA4
  #undef RDB4
  #undef CL8

  const int crow0 = brow * 256 + wr * 16 + lhi * 4;
  const int ccol0 = bcol * 256 + wc * 16 + lr;
  unsigned short* Cp = C + (unsigned long long)ksp * cstride;
  #pragma unroll
  for (int m = 0; m < 8; ++m)
    #pragma unroll
    for (int n = 0; n < 4; ++n)
      #pragma unroll
      for (int j = 0; j < 4; ++j)
        Cp[(size_t)(crow0 + m * 32 + j) * ldc + ccol0 + n * 64] = f2bf(acc[m][n][j]);

  // ---- fused attn write: rows r0..r0+63, cols k0..k0+kchunk ---------------
  {
    const int r0 = brow * 256 + bcol * 64;
    const int nch = kchunk >> 3;    // 8-byte chunks per row
    for (int idx = t; idx < 64 * nch; idx += 512) {
      const int row = idx / nch, ch = idx % nch;
      const float inv = sinvp[r0 + row];
      const unsigned long long bv =
          *(const unsigned long long*)(A + (size_t)(r0 + row) * ld + k0 + ch * 8);
      float4 f0, f1;
      #pragma unroll
      for (int j = 0; j < 8; ++j) {
        const float x = fp82f((uint8_t)(bv >> (8 * j)));
        const float a = (1.f + 0.0625f * x) * inv;
        if (j < 4) (&f0.x)[j] = a; else (&f1.x)[j - 4] = a;
      }
      float* arow = attnp + (size_t)(r0 + row) * NM + k0 + ch * 8;
      *(float4*)arow = f0;
      *(float4*)(arow + 4) = f1;
    }
  }
}

// ---- reduce: mf = (colsum[d] + sum_k bf16 part[k]) * sinv[row], S = 4 ------
__global__ void reduce_kernel(const unsigned short* __restrict__ part,
                              float4* __restrict__ mf,
                              const float* __restrict__ sinv,
                              const float* __restrict__ colsum) {
  const size_t n4 = (size_t)NB * ND / 4;
  const size_t ps = (size_t)NB * ND;
  for (size_t i = (size_t)blockIdx.x * blockDim.x + threadIdx.x; i < n4;
       i += (size_t)gridDim.x * blockDim.x) {
    const float is = sinv[i >> 8];
    const float4 c4 = ((const float4*)colsum)[i & 255];
    float s0 = 0, s1 = 0, s2 = 0, s3 = 0;
    #pragma unroll
    for (int k = 0; k < 4; ++k) {
      ushort4 p = ((const ushort4*)(part + (size_t)k * ps))[i];
      s0 += bf2f(p.x); s1 += bf2f(p.y); s2 += bf2f(p.z); s3 += bf2f(p.w);
    }
    float4 o;
    o.x = (s0 + c4.x) * is; o.y = (s1 + c4.y) * is;
    o.z = (s2 + c4.z) * is; o.w = (s3 + c4.w) * is;
    mf[i] = o;
  }
}

extern "C" void kernel_launch(void* const* d_in, const int* in_sizes, int n_in,
                              void* d_out, int out_size, void* d_ws, size_t ws_size,
                              hipStream_t stream) {
  const float* q   = (const float*)d_in[0];
  const float* mem = (const float*)d_in[1];
  float* mf   = (float*)d_out;                       // [4096 x 1024]
  float* attn = (float*)d_out + (size_t)NB * ND;     // [4096 x 8192]
  char* ws = (char*)d_ws;
  uint8_t* memn8       = (uint8_t*)(ws);                               // 8 MiB
  unsigned short* memn = (unsigned short*)(ws + ((size_t)8  << 20));   // 16 MiB
  uint8_t* memt8       = (uint8_t*)(ws + ((size_t)24 << 20));          // 8 MiB
  uint8_t* X8          = (uint8_t*)(ws + ((size_t)32 << 20));          // 32 MiB
  float* psum          = (float*)(ws + ((size_t)64 << 20));            // 512 KiB
  float* sinv          = (float*)(ws + ((size_t)64 << 20) + (512 << 10)); // 16 KiB
  float* colpart       = (float*)(ws + ((size_t)65 << 20));            // 128 KiB
  float* colsum        = (float*)(ws + ((size_t)65 << 20) + (512 << 10)); // 4 KiB
  unsigned short* part = (unsigned short*)(ws + ((size_t)66 << 20));   // 32 MiB (bf16 x4)
  uint8_t* qn8         = (uint8_t*)(ws + ((size_t)130 << 20));         // 4 MiB

  hipFuncSetAttribute((const void*)gemm4x,
                      hipFuncAttributeMaxDynamicSharedMemorySize, 131072);
  hipFuncSetAttribute((const void*)gemm4y,
                      hipFuncAttributeMaxDynamicSharedMemorySize, 131072);

  hipLaunchKernelGGL(nrm_m8, dim3(NM), dim3(256), 0, stream, mem, memn, memn8);
  hipLaunchKernelGGL(nrm_q8, dim3(NB), dim3(256), 0, stream, q, qn8);
  hipLaunchKernelGGL(tr8_kernel, dim3(ND / 64, NM / 64), dim3(256), 0, stream, memn, memt8);
  hipLaunchKernelGGL(colsum_part, dim3(4, 32), dim3(256), 0, stream, memn, colpart);
  hipLaunchKernelGGL(colred, dim3(4), dim3(256), 0, stream, colpart, colsum);

  // X8 = fp8(16*(exp(qn8*memn8^T)-1)) + psum : MX-fp8, M=4096, N=8192, K=1024.
  hipLaunchKernelGGL(gemm4x, dim3((NB / 256) * (NM / 256)), dim3(512), 131072, stream,
                     qn8, memn8, X8, psum, ND, NM, NB / 256, ND);

  hipLaunchKernelGGL(sinv_kernel, dim3(NB / 256), dim3(256), 0, stream, psum, sinv);

  // part[k] (bf16) = (X8*2^-4)*memt8^T (k-slice) + fused attn = (1+X/16)*sinv
  const int tps = (NB / 256) * (ND / 256);   // 64
  hipLaunchKernelGGL(gemm4y, dim3(tps * 4), dim3(512), 131072, stream,
                     X8, memt8, part, sinv, attn, NM, ND, NB / 256, tps, NM / 4,
                     (unsigned long long)NB * ND);
  hipLaunchKernelGGL(reduce_kernel, dim3(2048), dim3(256), 0, stream,
                     part, (float4*)mf, sinv, colsum);
}